// Round 8
// baseline (101.444 us; speedup 1.0000x reference)
//
#include <hip/hip_runtime.h>
#include <cstdint>
#include <cstddef>

// SpectralGraphConv: B=8, N=1024, C_IN=C_OUT=64, K=4
//   z0 = x, z1 = L x, z_k = 2 L z_{k-1} - z_{k-2},  out = sum_k z_k @ theta[k]
//
// Round-8: fold L f32->bf16 conversion INTO stage 1 (its WGs partition L's
// rows 1:1, and its B-frags already hold the converted bf16 values -> waves
// wq==0 store b0/b1 straight to Lb). Prep shrinks to x/theta only (132 WGs).
// Net: -33MB HBM (prep's L read deleted), one cheap dispatch instead of a
// 50MB pass. Stage 1: D=4 x 16KB LDS buffers (f32 L 8KB + zT 8KB), counted
// vmcnt 4/2/0 (2 DMA events/wave/step; extra stores only inflate waves 0/4's
// counter -> conservative). Stages 2-3 byte-identical to verified round-7.

typedef __bf16 bf16;
typedef bf16 bf16x8 __attribute__((ext_vector_type(8)));
typedef float f32x4 __attribute__((ext_vector_type(4)));

#define MFMA_BF16(a, b, c) __builtin_amdgcn_mfma_f32_16x16x32_bf16((a), (b), (c), 0, 0, 0)
#define WAITV(n) asm volatile("s_waitcnt vmcnt(" #n ")" ::: "memory")

__device__ __forceinline__ void dma16(const void* g, void* l) {
    __builtin_amdgcn_global_load_lds(
        (const __attribute__((address_space(1))) unsigned int*)g,
        (__attribute__((address_space(3))) unsigned int*)l, 16, 0, 0);
}

// ---------------------------------------------------------------------------
// prep: blocks 0..127: x -> xT (bf16 [b][c][n]) + xb (bf16 [b][n][c])
//       blocks 128..131: theta -> thT (bf16 [k][o][c])
// ---------------------------------------------------------------------------
__global__ __launch_bounds__(256) void prep_kernel(const float* __restrict__ x,
                                                   const float* __restrict__ theta,
                                                   bf16* __restrict__ xT,
                                                   bf16* __restrict__ xb,
                                                   bf16* __restrict__ thT)
{
    __shared__ bf16 tile[64][72];
    const int bid = blockIdx.x;
    const int t = threadIdx.x;
    const int r = t >> 2;
    const int c0 = (t & 3) << 4;
    const float* src;
    bf16* dstT;
    int dst_ld;
    const bool isx = bid < 128;
    int b = 0, n0 = 0;
    if (isx) {
        b = bid >> 4; n0 = (bid & 15) << 6;
        src = x + (size_t)(b * 1024 + n0) * 64;
        dstT = xT + (size_t)b * 64 * 1024 + n0;
        dst_ld = 1024;
    } else {
        const int k = bid - 128;
        src = theta + (size_t)k * 4096;
        dstT = thT + (size_t)k * 4096;
        dst_ld = 64;
    }

    bf16x8 row0, row1;
#pragma unroll
    for (int j = 0; j < 16; j += 4) {
        f32x4 v = *reinterpret_cast<const f32x4*>(src + r * 64 + c0 + j);
#pragma unroll
        for (int i = 0; i < 4; ++i) {
            bf16 q = (bf16)v[i];
            tile[r][c0 + j + i] = q;
            if (j + i < 8) row0[j + i] = q; else row1[j + i - 8] = q;
        }
    }
    if (isx) {
        bf16* xr = xb + (size_t)(b * 1024 + n0 + r) * 64 + c0;
        *reinterpret_cast<bf16x8*>(xr) = row0;
        *reinterpret_cast<bf16x8*>(xr + 8) = row1;
    }
    __syncthreads();
    bf16x8 o0, o1;
#pragma unroll
    for (int j = 0; j < 8; ++j) { o0[j] = tile[c0 + j][r]; o1[j] = tile[c0 + 8 + j][r]; }
    *reinterpret_cast<bf16x8*>(dstT + (size_t)r * dst_ld + c0) = o0;
    *reinterpret_cast<bf16x8*>(dstT + (size_t)r * dst_ld + c0 + 8) = o1;
}

// ---------------------------------------------------------------------------
// stage 1: WG = 8 waves (512 thr), 32-row m-tile; reads f32 L, writes Lb bf16.
// wave w: chan-group wq=w&3, m-half h=w>>2.
// LDS/step: f32 L 32x64 (8KB) + zT 64x64 bf16 (8KB); D=4 -> 64KB.
// 16B-granule XOR swizzle (slot ^ (row&7)) per verified round-3/7 math.
// ---------------------------------------------------------------------------
__global__ __launch_bounds__(512) void stage1_kernel(
    const float* __restrict__ Lmat,    // [b][m][k] f32
    const bf16* __restrict__ xb,       // [b][n][c] bf16
    const bf16* __restrict__ zinT,     // [b][c][n] bf16 = xT
    const bf16* __restrict__ thT,      // [k][o][c] bf16
    bf16* __restrict__ Lb,             // [b][m][k] bf16 (written here)
    bf16* __restrict__ zoutT,          // [b][c][n] bf16 = z1T
    float* __restrict__ out)           // [b][n][o] f32
{
    constexpr int D = 4, T = 16, KS = 64, LSTG = 16384;
    __shared__ __align__(16) unsigned char smem[D * LSTG];   // 65536 B

    const int bid = blockIdx.x;
    const int b  = bid >> 5;
    const int m0 = (bid & 31) << 5;
    const int t  = threadIdx.x;
    const int w  = t >> 6;
    const int l  = t & 63;
    const int l15 = l & 15;
    const int lg  = l >> 4;
    const int wq  = w & 3;
    const int h   = w >> 2;

    const float* Lrb = Lmat + ((size_t)(b * 1024 + m0)) * 1024;
    const bf16*  zb  = zinT + (size_t)b * 64 * 1024;

    // L (f32): 512 granules/step (32 rows x 16); thread t: row=t>>4, slot=t&15
    const int Lrow = t >> 4, Lslot = t & 15;
    const float* Lsrc = Lrb + (size_t)Lrow * 1024 + ((Lslot ^ (Lrow & 7)) << 2);
    // Z (bf16): 512 granules/step (64 chans x 8); g = t
    const int Zg = (w << 6) + l;
    const int Zch = Zg >> 3;
    const bf16* Zsrc = zb + (size_t)Zch * 1024 + ((Zg & 7) ^ (Zch & 7)) * 8;

    auto issue = [&](int k0, unsigned char* bufb) {
        dma16(Lsrc + k0, bufb + (w << 10));           // L half of buffer
        dma16(Zsrc + k0, bufb + 8192 + (w << 10));    // Z half
    };

    f32x4 acc = {0.f, 0.f, 0.f, 0.f};
    const int mrow = (h << 4) + l15;
    bf16* Lbrow = Lb + (size_t)(b * 1024 + m0 + mrow) * 1024;

    auto computeStep = [&](const unsigned char* bufb, int k0) {
        const float* Ll = (const float*)bufb;
        const bf16*  Zl = (const bf16*)(bufb + 8192);
        const int chan = (wq << 4) + l15;
        const int sA = chan & 7;
        bf16x8 a0 = *(const bf16x8*)(Zl + (((chan << 3) + (lg ^ sA)) << 3));
        bf16x8 a1 = *(const bf16x8*)(Zl + (((chan << 3) + ((4 + lg) ^ sA)) << 3));
        const int sB = mrow & 7;
        const float* Lr = Ll + (mrow << 6);
        f32x4 u0 = *(const f32x4*)(Lr + ((((lg << 1) | 0) ^ sB) << 2));
        f32x4 u1 = *(const f32x4*)(Lr + ((((lg << 1) | 1) ^ sB) << 2));
        f32x4 v0 = *(const f32x4*)(Lr + (((8 + ((lg << 1) | 0)) ^ sB) << 2));
        f32x4 v1 = *(const f32x4*)(Lr + (((8 + ((lg << 1) | 1)) ^ sB) << 2));
        bf16x8 b0, b1;
#pragma unroll
        for (int j = 0; j < 4; ++j) {
            b0[j] = (bf16)u0[j]; b0[4 + j] = (bf16)u1[j];
            b1[j] = (bf16)v0[j]; b1[4 + j] = (bf16)v1[j];
        }
        if (wq == 0) {   // waves 0,4 own unique (m,k) coverage: write Lb
            *reinterpret_cast<bf16x8*>(Lbrow + k0 + (lg << 3))      = b0;
            *reinterpret_cast<bf16x8*>(Lbrow + k0 + 32 + (lg << 3)) = b1;
        }
        acc = MFMA_BF16(a0, b0, acc);
        acc = MFMA_BF16(a1, b1, acc);
    };

    // prologue: D-1 steps in flight
#pragma unroll
    for (int s = 0; s < D - 1; ++s)
        issue(s * KS, smem + s * LSTG);

#pragma unroll
    for (int tt = 0; tt < T; ++tt) {
        const int rem = ((T - tt) < (D - 1) ? (T - tt) : (D - 1)) - 1;
        if (rem >= 2)      WAITV(4);
        else if (rem == 1) WAITV(2);
        else               WAITV(0);
        __builtin_amdgcn_sched_barrier(0);
        __builtin_amdgcn_s_barrier();
        __builtin_amdgcn_sched_barrier(0);
        computeStep(smem + (tt % D) * LSTG, tt * KS);
        __builtin_amdgcn_sched_barrier(0);
        if (tt + D - 1 < T)
            issue((tt + D - 1) * KS, smem + ((tt + D - 1) % D) * LSTG);
        __builtin_amdgcn_sched_barrier(0);
    }

    // ---- epilogue: z1 = acc; write z1T; theta phase -----------------------
    // zbuf aliased onto buffer 1 (last read computeStep(13), safe post-loop).
    bf16 (*zbuf)[72] = (bf16(*)[72])(smem + LSTG);
    const int cr   = (wq << 4) + (lg << 2);
    const int mcol = m0 + (h << 4) + l15;
    float zv[4];
#pragma unroll
    for (int r = 0; r < 4; ++r) zv[r] = acc[r];
#pragma unroll
    for (int r = 0; r < 4; ++r)
        zoutT[(size_t)(b * 64 + cr + r) * 1024 + mcol] = (bf16)zv[r];
#pragma unroll
    for (int r = 0; r < 4; ++r)
        zbuf[(h << 4) + l15][cr + r] = (bf16)zv[r];
    __syncthreads();

    const int o = (wq << 4) + l15;
    const int mrowA = m0 + (h << 4) + l15;
    f32x4 oacc = {0.f, 0.f, 0.f, 0.f};
#pragma unroll
    for (int ck = 0; ck < 2; ++ck) {        // x @ theta[0]
        bf16x8 ax = *reinterpret_cast<const bf16x8*>(
            xb + (size_t)(b * 1024 + mrowA) * 64 + ck * 32 + lg * 8);
        bf16x8 bt = *reinterpret_cast<const bf16x8*>(
            thT + (size_t)o * 64 + ck * 32 + lg * 8);
        oacc = MFMA_BF16(ax, bt, oacc);
    }
#pragma unroll
    for (int ck = 0; ck < 2; ++ck) {        // z1 @ theta[1]
        bf16x8 az = *reinterpret_cast<const bf16x8*>(
            &zbuf[(h << 4) + l15][ck * 32 + lg * 8]);
        bf16x8 bt = *reinterpret_cast<const bf16x8*>(
            thT + (size_t)(64 + o) * 64 + ck * 32 + lg * 8);
        oacc = MFMA_BF16(az, bt, oacc);
    }
#pragma unroll
    for (int r = 0; r < 4; ++r)
        out[(size_t)(b * 1024 + m0 + (h << 4) + lg * 4 + r) * 64 + o] = oacc[r];
}

// ---------------------------------------------------------------------------
// stages 2,3: byte-identical to verified round-7 kernel.
// ---------------------------------------------------------------------------
template <int STAGE>
__global__ __launch_bounds__(512) void stage_kernel(
    const bf16* __restrict__ Lb,       // [b][m][k] bf16
    const bf16* __restrict__ xb,       // unused here
    const bf16* __restrict__ zinT,     // [b][c][n] bf16 (A operand)
    const bf16* __restrict__ zprevT,   // [b][c][n] bf16 (subtract)
    const bf16* __restrict__ thT,      // [k][o][c] bf16
    bf16* __restrict__ zoutT,          // [b][c][n] bf16 (stage 2)
    float* __restrict__ out)           // [b][n][o] f32
{
    constexpr int D = 5, T = 16, KS = 64, LSTG = 12288;
    __shared__ __align__(16) unsigned char smem[D * LSTG];   // 61440 B

    const int bid = blockIdx.x;
    const int b  = bid >> 5;
    const int m0 = (bid & 31) << 5;
    const int t  = threadIdx.x;
    const int w  = t >> 6;
    const int l  = t & 63;
    const int l15 = l & 15;
    const int lg  = l >> 4;
    const int wq  = w & 3;
    const int h   = w >> 2;

    const bf16* Lrb = Lb + ((size_t)(b * 1024 + m0)) * 1024;
    const bf16* zb  = zinT + (size_t)b * 64 * 1024;

    const int Lg = (w << 5) + (l & 31);
    const int Lrow = Lg >> 3, Lslot = Lg & 7;
    const bf16* Lsrc = Lrb + (size_t)Lrow * 1024 + (Lslot ^ (Lrow & 7)) * 8;
    const int Zg = (w << 6) + l;
    const int Zch = Zg >> 3;
    const bf16* Zsrc = zb + (size_t)Zch * 1024 + ((Zg & 7) ^ (Zch & 7)) * 8;

    auto issue = [&](int k0, unsigned char* bufb) {
        dma16(Zsrc + k0, bufb + 4096 + (w << 10));
        if (l < 32)
            dma16(Lsrc + k0, bufb + (w << 9));
    };

    f32x4 acc = {0.f, 0.f, 0.f, 0.f};

    auto computeStep = [&](const unsigned char* bufb) {
        const bf16* Ll = (const bf16*)bufb;
        const bf16* Zl = (const bf16*)(bufb + 4096);
        const int chan = (wq << 4) + l15;
        const int sA = chan & 7;
        bf16x8 a0 = *(const bf16x8*)(Zl + (((chan << 3) + (lg ^ sA)) << 3));
        bf16x8 a1 = *(const bf16x8*)(Zl + (((chan << 3) + ((4 + lg) ^ sA)) << 3));
        const int mrow = (h << 4) + l15;
        const int sB = mrow & 7;
        bf16x8 b0 = *(const bf16x8*)(Ll + (((mrow << 3) + (lg ^ sB)) << 3));
        bf16x8 b1 = *(const bf16x8*)(Ll + (((mrow << 3) + ((4 + lg) ^ sB)) << 3));
        acc = MFMA_BF16(a0, b0, acc);
        acc = MFMA_BF16(a1, b1, acc);
    };

#pragma unroll
    for (int s = 0; s < D - 1; ++s)
        issue(s * KS, smem + s * LSTG);

#pragma unroll
    for (int tt = 0; tt < T; ++tt) {
        const int rem = ((T - tt) < (D - 1) ? (T - tt) : (D - 1)) - 1;
        if (rem >= 3)      WAITV(6);
        else if (rem == 2) WAITV(4);
        else if (rem == 1) WAITV(2);
        else               WAITV(0);
        __builtin_amdgcn_sched_barrier(0);
        __builtin_amdgcn_s_barrier();
        __builtin_amdgcn_sched_barrier(0);
        computeStep(smem + (tt % D) * LSTG);
        if (tt + D - 1 < T)
            issue((tt + D - 1) * KS, smem + ((tt + D - 1) % D) * LSTG);
    }

    bf16 (*zbuf)[72] = (bf16(*)[72])(smem + LSTG);
    const int cr   = (wq << 4) + (lg << 2);
    const int mcol = m0 + (h << 4) + l15;
    float zv[4];
#pragma unroll
    for (int r = 0; r < 4; ++r) {
        float zp = (float)zprevT[(size_t)(b * 64 + cr + r) * 1024 + mcol];
        zv[r] = 2.0f * acc[r] - zp;
    }
    if constexpr (STAGE <= 2) {
#pragma unroll
        for (int r = 0; r < 4; ++r)
            zoutT[(size_t)(b * 64 + cr + r) * 1024 + mcol] = (bf16)zv[r];
    }
#pragma unroll
    for (int r = 0; r < 4; ++r)
        zbuf[(h << 4) + l15][cr + r] = (bf16)zv[r];
    __syncthreads();

    const int o = (wq << 4) + l15;
    f32x4 oacc;
#pragma unroll
    for (int r = 0; r < 4; ++r)
        oacc[r] = out[(size_t)(b * 1024 + m0 + (h << 4) + lg * 4 + r) * 64 + o];
    constexpr int KTH = STAGE;
#pragma unroll
    for (int ck = 0; ck < 2; ++ck) {
        bf16x8 az = *reinterpret_cast<const bf16x8*>(
            &zbuf[(h << 4) + l15][ck * 32 + lg * 8]);
        bf16x8 bt = *reinterpret_cast<const bf16x8*>(
            thT + (size_t)(KTH * 64 + o) * 64 + ck * 32 + lg * 8);
        oacc = MFMA_BF16(az, bt, oacc);
    }
#pragma unroll
    for (int r = 0; r < 4; ++r)
        out[(size_t)(b * 1024 + m0 + (h << 4) + lg * 4 + r) * 64 + o] = oacc[r];
}

// ---------------------------------------------------------------------------
extern "C" void kernel_launch(void* const* d_in, const int* in_sizes, int n_in,
                              void* d_out, int out_size, void* d_ws, size_t ws_size,
                              hipStream_t stream)
{
    const float* x  = (const float*)d_in[0];    // [8,1024,64]
    const float* L  = (const float*)d_in[1];    // [8,1024,1024]
    const float* th = (const float*)d_in[2];    // [4,64,64]
    float* out = (float*)d_out;                 // [8,1024,64]

    // ws (bf16): xT | xb | z1T | z2T | thT | Lb  (~20 MB)
    bf16* xT  = (bf16*)d_ws;
    bf16* xb  = xT  + (size_t)8 * 64 * 1024;
    bf16* z1T = xb  + (size_t)8 * 64 * 1024;
    bf16* z2T = z1T + (size_t)8 * 64 * 1024;
    bf16* thT = z2T + (size_t)8 * 64 * 1024;
    bf16* Lb  = thT + (size_t)4 * 64 * 64;

    prep_kernel<<<dim3(132), dim3(256), 0, stream>>>(x, th, xT, xb, thT);
    // stage 1: z1 = L x;  out = x@th0 + z1@th1;  Lb written as side product
    stage1_kernel<<<dim3(256), dim3(512), 0, stream>>>(L, xb, xT, thT, Lb, z1T, out);
    // stage 2: z2 = 2 L z1 - x;     out += z2@th2
    stage_kernel<2><<<dim3(256), dim3(512), 0, stream>>>(Lb, xb, z1T, xT, thT, z2T, out);
    // stage 3: z3 = 2 L z2 - z1;    out += z3@th3
    stage_kernel<3><<<dim3(256), dim3(512), 0, stream>>>(Lb, xb, z2T, z1T, thT, nullptr, out);
}